// Round 1
// baseline (10.792 us; speedup 1.0000x reference)
//
#include <hip/hip_runtime.h>

// GCNet cost-volume + soft-argmax, MI355X.
// Fixed problem: B=1, C=32, H=128, W=256, min_disp=0, max_disp=128 -> D=64.
// feaL is unused by the reference math (left branch multiplies feaR).
//
// Right-channel softargmax rewritten as sliding-window sums over per-row
// exp prefix sums (no per-window max needed: inputs are N(0,1), exp safe).

#define CC 32
#define HH 128
#define WW 256

__global__ __launch_bounds__(256) void gcnet_kernel(const float* __restrict__ feaR,
                                                    float* __restrict__ out) {
    const int w    = threadIdx.x;      // column 0..255
    const int lane = w & 63;
    const int wid  = w >> 6;           // wave id 0..3

    __shared__ float sP[WW];
    __shared__ float sQ[WW];
    __shared__ float wPs[4];
    __shared__ float wQs[4];

    for (int r = blockIdx.x; r < CC * HH; r += gridDim.x) {
        // r = c*H + h  (H = 128)
        const int c = r >> 7;
        const int h = r & 127;

        const float v = feaR[(size_t)r * WW + w];
        const float e = __expf(v);

        // ---- block-wide inclusive scans of e and w*e ----
        float p = e;
        float q = e * (float)w;
        #pragma unroll
        for (int off = 1; off < 64; off <<= 1) {
            float pu = __shfl_up(p, off, 64);
            float qu = __shfl_up(q, off, 64);
            if (lane >= off) { p += pu; q += qu; }
        }
        if (lane == 63) { wPs[wid] = p; wQs[wid] = q; }
        __syncthreads();
        #pragma unroll
        for (int j = 0; j < 3; ++j) {
            if (wid > j) { p += wPs[j]; q += wQs[j]; }
        }
        sP[w] = p;
        sQ[w] = q;
        __syncthreads();

        // ---- right channel (output channel c+32) ----
        // cost[d] = feaR[c,h,w-d] for d<=w else 0;  d in [0,64)
        float dP = p - (w >= 64 ? sP[w - 64] : 0.0f);
        float dQ = q - (w >= 64 ? sQ[w - 64] : 0.0f);
        float num = (float)w * dP - dQ;
        float den = dP;
        if (w < 63) {
            // n0 = 63-w zero entries (exp(0)=1 each), their d-sum S0 = 2016 - w(w+1)/2
            float S1 = 0.5f * (float)w * (float)(w + 1);
            num += 2016.0f - S1;
            den += (float)(63 - w);
        }
        out[((size_t)(CC + c) * HH + h) * WW + w] = num / den;

        // ---- left channel (output channel c) ----
        // cost[d] = v for d<=w else 0 -> two-valued softmax closed form
        float n1  = (w >= 63) ? 64.0f : (float)(w + 1);
        float S1l = 0.5f * n1 * (n1 - 1.0f);
        float n0  = 64.0f - n1;
        float S0l = 2016.0f - S1l;
        out[((size_t)c * HH + h) * WW + w] = (S1l * e + S0l) / (n1 * e + n0);

        __syncthreads();  // protect sP/sQ/wPs before next row
    }
}

extern "C" void kernel_launch(void* const* d_in, const int* in_sizes, int n_in,
                              void* d_out, int out_size, void* d_ws, size_t ws_size,
                              hipStream_t stream) {
    const float* feaR = (const float*)d_in[1];  // d_in[0] = feaL (unused)
    float* out = (float*)d_out;
    dim3 grid(CC * HH);   // 4096 blocks, one feaR row each
    dim3 block(WW);       // 256 threads = 4 waves
    gcnet_kernel<<<grid, block, 0, stream>>>(feaR, out);
}

// Round 2
// 10.503 us; speedup vs baseline: 1.0275x; 1.0275x over previous
//
#include <hip/hip_runtime.h>

// GCNet cost-volume + soft-argmax, MI355X. B=1, C=32, H=128, W=256, D=64.
// feaL is unused by the reference math (left branch multiplies feaR).
//
// One wave per row, 4 elements/thread:
//   - float4 coalesced load: one wave reads the whole 256-elem row
//   - softmax-free reformulation: e=exp(x) once per element (N(0,1) inputs,
//     no overflow risk; softmax is shift-invariant so no max needed)
//   - in-register 4-elem prefix + 6-step wave shuffle scan -> P=prefix(e),
//     Q=prefix(w*e); window-64 sums via single shfl from lane t-16
//   - zero LDS, zero __syncthreads

#define CC 32
#define HH 128
#define WW 256

__global__ __launch_bounds__(256) void gcnet_kernel(const float* __restrict__ feaR,
                                                    float* __restrict__ out) {
    const int t   = threadIdx.x & 63;   // lane in wave
    const int wid = threadIdx.x >> 6;   // wave id 0..3
    const int r   = (blockIdx.x << 2) + wid;  // row = c*H + h, r < 4096
    const int c   = r >> 7;
    const int h   = r & 127;

    const float4 v = *reinterpret_cast<const float4*>(feaR + ((size_t)r << 8) + (t << 2));

    const float e0 = __expf(v.x);
    const float e1 = __expf(v.y);
    const float e2 = __expf(v.z);
    const float e3 = __expf(v.w);

    const float w0 = (float)(t << 2);

    // in-thread inclusive prefixes of e and w*e
    const float p0 = e0, p1 = p0 + e1, p2 = p1 + e2, p3 = p2 + e3;
    const float q0 = e0 * w0;
    const float q1 = q0 + e1 * (w0 + 1.0f);
    const float q2 = q1 + e2 * (w0 + 2.0f);
    const float q3 = q2 + e3 * (w0 + 3.0f);

    // wave-wide inclusive scan of thread totals (two independent chains -> ILP)
    float sp = p3, sq = q3;
    #pragma unroll
    for (int off = 1; off < 64; off <<= 1) {
        float a = __shfl_up(sp, off, 64);
        float b = __shfl_up(sq, off, 64);
        if (t >= off) { sp += a; sq += b; }
    }
    const float offP = sp - p3;
    const float offQ = sq - q3;

    const float P0 = offP + p0, P1 = offP + p1, P2 = offP + p2, P3 = offP + p3;
    const float Q0 = offQ + q0, Q1 = offQ + q1, Q2 = offQ + q2, Q3 = offQ + q3;

    // P,Q at column w-64  == same sub-element of lane t-16
    const int src = (t - 16) & 63;
    const float Pm0 = __shfl(P0, src, 64), Pm1 = __shfl(P1, src, 64);
    const float Pm2 = __shfl(P2, src, 64), Pm3 = __shfl(P3, src, 64);
    const float Qm0 = __shfl(Q0, src, 64), Qm1 = __shfl(Q1, src, 64);
    const float Qm2 = __shfl(Q2, src, 64), Qm3 = __shfl(Q3, src, 64);

    const bool hi = (t >= 16);   // w >= 64 for all 4 sub-elements

    float4 right, left;
    {
        float P[4]  = {P0, P1, P2, P3};
        float Q[4]  = {Q0, Q1, Q2, Q3};
        float PM[4] = {Pm0, Pm1, Pm2, Pm3};
        float QM[4] = {Qm0, Qm1, Qm2, Qm3};
        float E[4]  = {e0, e1, e2, e3};
        float R[4], L[4];
        #pragma unroll
        for (int j = 0; j < 4; ++j) {
            const float wj = w0 + (float)j;
            // ---- right channel: cost[d] = feaR[c,h,w-d] (d<=w), else 0
            float dP = P[j] - (hi ? PM[j] : 0.0f);
            float dQ = Q[j] - (hi ? QM[j] : 0.0f);
            float num = wj * dP - dQ;
            float den = dP;
            if (wj < 63.0f) {
                float S1 = 0.5f * wj * (wj + 1.0f);
                num += 2016.0f - S1;       // zero-pad entries contribute e^0=1 each
                den += 63.0f - wj;
            }
            R[j] = num / den;
            // ---- left channel: cost[d] = v (d<=w), else 0 -> closed form
            float n1  = fminf(wj + 1.0f, 64.0f);
            float S1l = 0.5f * n1 * (n1 - 1.0f);
            float n0  = 64.0f - n1;
            float S0l = 2016.0f - S1l;
            L[j] = (S1l * E[j] + S0l) / (n1 * E[j] + n0);
        }
        right = make_float4(R[0], R[1], R[2], R[3]);
        left  = make_float4(L[0], L[1], L[2], L[3]);
    }

    float* outR = out + (((size_t)(CC + c) * HH + h) << 8) + (t << 2);
    float* outL = out + (((size_t)c * HH + h) << 8) + (t << 2);
    *reinterpret_cast<float4*>(outR) = right;
    *reinterpret_cast<float4*>(outL) = left;
}

extern "C" void kernel_launch(void* const* d_in, const int* in_sizes, int n_in,
                              void* d_out, int out_size, void* d_ws, size_t ws_size,
                              hipStream_t stream) {
    const float* feaR = (const float*)d_in[1];  // d_in[0] = feaL (unused)
    float* out = (float*)d_out;
    dim3 grid((CC * HH) / 4);   // 1024 blocks, 4 waves each, one row per wave
    dim3 block(256);
    gcnet_kernel<<<grid, block, 0, stream>>>(feaR, out);
}